// Round 13
// baseline (80.265 us; speedup 1.0000x reference)
//
#include <hip/hip_runtime.h>

// Problem constants (MemoryGraph_15453292331249)
constexpr int N  = 8192;
constexpr int K  = 32;
constexpr int D  = 32;
constexpr int BS = 2;
constexpr int T  = 16;
constexpr int C  = 64;
constexpr int H  = 64;
constexpr int MOD_IN = 5 * D;   // 160
constexpr int STRIDE = 4;
constexpr int NPB = 8;          // neurons (32-lane groups) per block
constexpr int LIST_LEN = C * (K + 1);   // 2112 (with benign duplicates)

__device__ __forceinline__ float sigmoidf_(float x) { return 1.0f / (1.0f + expf(-x)); }

// ===========================================================================
// MEASUREMENT ROUND: kernel code is identical to R12. Kernel A is launched
// 3x (idempotent: all outputs are pure functions of the inputs), so
// A = (dur - 45.6)/2. This decides F-dominated vs A-dominated attribution.
// ===========================================================================

// ===========================================================================
// Kernel A — phase1 hot path (+ fused step 0). Barrier-free; register-batched
// gather (R12-proven).
// ===========================================================================
__global__ __launch_bounds__(256) void phase1_step0_kernel(
    const float* __restrict__ cc,          // (BS,T,C,D)
    const float* __restrict__ h_prev,      // (BS,N,D)
    const float* __restrict__ prev_msgs,   // (BS,N,D)
    const float* __restrict__ trace_prim,  // (BS,N,D)
    const float* __restrict__ trace_key,   // (BS,N,D)
    const float* __restrict__ primitives,  // (N,D)
    const float* __restrict__ key_w,       // (N,D)
    const float* __restrict__ decay_logit, // (N,)
    const float* __restrict__ bw,          // (N,K,D)
    const float* __restrict__ gw,          // (N,4,32)
    const float* __restrict__ fc2_w,       // (N,64,3)
    const float* __restrict__ fc2_b,       // (N,3)
    const float* __restrict__ mod_lr_logit,// (1,)
    const int*   __restrict__ conn,        // (N,K)
    float*  __restrict__ ws_ed,            // (BS,N)
    float*  __restrict__ ws_ep,            // (BS,N,D)
    float*  __restrict__ ws_rt,            // (BS,N,K)
    float4* __restrict__ ws_u,             // (N) {bw_uni, w0, gw_uni, g0}
    int*    __restrict__ ws_fl,            // (N) fc2_w-nonzero flag
    float*  __restrict__ ws_h,             // (BS,N,D) h after step 0
    float*  __restrict__ ws_m0,            // (BS,N,D) msgs after step 0
    int*    __restrict__ ws_list,          // (LIST_LEN)
    float*  __restrict__ out)              // (BS,T,C,D)
{
    const int t   = threadIdx.x;
    const int sub = t >> 5;
    const int d   = t & 31;
    const int n   = blockIdx.x * NPB + sub;

    __shared__ __align__(16) float ek_s[NPB][2][D];
    __shared__ __align__(16) float rows[NPB][K][36];
    __shared__ float rts[NPB][K];

    // ---- fc2_w slice zero-check -> flag (rescue kernel handles nonzero)
    const float* f2w = fc2_w + n * (H * 3);
    int nzf = 0;
    #pragma unroll
    for (int i = 0; i < 6; ++i) nzf |= (f2w[i * 32 + d] != 0.0f);
    #pragma unroll
    for (int m = 1; m < 32; m <<= 1) nzf |= __shfl_xor(nzf, m);
    if (d == 0) ws_fl[n] = nzf;

    // ---- o3 = fc2_b (fast path; garbage-if-nzf is overwritten by rescue)
    float o3[3];
    #pragma unroll
    for (int o = 0; o < 3; ++o) o3[o] = fc2_b[n * 3 + o];

    // ---- gates, eff_decay, eff_prim, eff_key
    const float mlr = sigmoidf_(mod_lr_logit[0]);
    float ep2[2], edc[2];
    #pragma unroll
    for (int b = 0; b < 2; ++b) {
        const size_t base = ((size_t)b * N + n) * D + d;
        const float tp = trace_prim[base];
        const float tk = trace_key[base];
        float sp = tp * tp, sk = tk * tk;
        #pragma unroll
        for (int m = 1; m < 32; m <<= 1) {
            sp += __shfl_xor(sp, m);
            sk += __shfl_xor(sk, m);
        }
        const float gate_prim = tanhf(o3[0]);
        const float gate_key  = tanhf(o3[1]);
        edc[b] = sigmoidf_(decay_logit[n] + o3[2]);
        if (d == 0) ws_ed[b * N + n] = edc[b];
        ep2[b] = primitives[n*D+d] + mlr*gate_prim*(tp / fmaxf(sqrtf(sp), 1e-8f));
        const float ekv = key_w[n*D+d] + mlr*gate_key *(tk / fmaxf(sqrtf(sk), 1e-8f));
        ws_ep[base] = ep2[b];
        ek_s[sub][b][d] = ekv;
    }

    // ---- bw/gw per-neuron uniformity check (contiguous float4 loads)
    const float* bwn = bw + (size_t)n * (K * D);
    const float* gwn = gw + (size_t)n * 128;
    const float w0v = bwn[0];
    const float g0v = gwn[0];
    int eqb = 1, eqg;
    {
        const float4* b4 = reinterpret_cast<const float4*>(bwn);
        #pragma unroll
        for (int q = 0; q < 8; ++q) {
            const float4 v = b4[q * 32 + d];
            eqb &= (v.x == w0v) & (v.y == w0v) & (v.z == w0v) & (v.w == w0v);
        }
        const float4 gv = reinterpret_cast<const float4*>(gwn)[d];
        eqg = (gv.x == g0v) & (gv.y == g0v) & (gv.z == g0v) & (gv.w == g0v);
    }
    #pragma unroll
    for (int m = 1; m < 32; m <<= 1) {
        eqb &= __shfl_xor(eqb, m);
        eqg &= __shfl_xor(eqg, m);
    }
    if (d == 0) ws_u[n] = make_float4(eqb ? 1.f : 0.f, w0v, eqg ? 1.f : 0.f, g0v);

    // ---- conn row (one load per lane; reused via shfl) + step-2 list
    const int jme = conn[n * K + d];
    if (n < C) {
        ws_list[n * (K + 1) + d] = jme;
        if (d == 0) ws_list[n * (K + 1) + K] = n;
    }

    // ---- fused scan step 0: register-batched gather
    const float gv0 = gwn[d], gv1 = gwn[32+d], gv2 = gwn[64+d], gv3 = gwn[96+d];
    #pragma unroll
    for (int b = 0; b < 2; ++b) {
        const float* mp = prev_msgs + (size_t)b * N * D;

        float r[32];
        #pragma unroll
        for (int k = 0; k < 32; ++k) {
            const int j = __shfl(jme, k, 32);
            r[k] = mp[(size_t)j * D + d];
        }

        #pragma unroll
        for (int k = 0; k < 32; ++k) rows[sub][k][d] = r[k];

        {
            const int k = d;
            const float4* rw = reinterpret_cast<const float4*>(rows[sub][k]);
            float s = 0.f;
            #pragma unroll
            for (int q = 0; q < 8; ++q) {
                const float4 v = rw[q];
                s += ek_s[sub][b][q*4+0]*v.x + ek_s[sub][b][q*4+1]*v.y +
                     ek_s[sub][b][q*4+2]*v.z + ek_s[sub][b][q*4+3]*v.w;
            }
            const float rtv = sigmoidf_(s);
            ws_rt[((size_t)b * N + n) * K + k] = rtv;
            rts[sub][k] = rtv;
        }

        {
            float bs[4] = {0.f, 0.f, 0.f, 0.f};
            if (eqb) {
                #pragma unroll
                for (int k = 0; k < 32; ++k)
                    bs[k >> 3] += rts[sub][k] * r[k];
                #pragma unroll
                for (int a = 0; a < 4; ++a) bs[a] *= w0v;
            } else {
                #pragma unroll
                for (int k = 0; k < 32; ++k)
                    bs[k >> 3] += rts[sub][k] * r[k] * bwn[k * 32 + d];
            }
            const float t0 = tanhf(bs[0]), t1 = tanhf(bs[1]),
                        t2 = tanhf(bs[2]), t3 = tanhf(bs[3]);
            const float gsum = eqg ? g0v * (t0 + t1 + t2 + t3)
                                   : t0*gv0 + t1*gv1 + t2*gv2 + t3*gv3;
            float rec = tanhf(gsum);
            const size_t tslot = (size_t)b * (T * C * D) + (size_t)n * D + d;  // t=0
            if (n < C) rec += cc[tslot];
            const float hn = edc[b] * h_prev[((size_t)b * N + n) * D + d]
                           + (1.f - edc[b]) * rec;
            const float msg = tanhf(hn * ep2[b]);
            ws_h[((size_t)b * N + n) * D + d]  = hn;
            ws_m0[((size_t)b * N + n) * D + d] = msg;
            if (n < C) {
                #pragma unroll
                for (int r2 = 0; r2 < STRIDE; ++r2)
                    out[tslot + (size_t)r2 * (C * D)] = msg;
            }
        }
    }
}

// ===========================================================================
// Rescue kernel — general path for neurons with nonzero fc2_w slice.
// ===========================================================================
__global__ __launch_bounds__(256) void rescue_kernel(
    const float* __restrict__ cc,
    const float* __restrict__ h_prev,
    const float* __restrict__ prev_msgs,
    const float* __restrict__ trace_prim,
    const float* __restrict__ trace_key,
    const float* __restrict__ primitives,
    const float* __restrict__ key_w,
    const float* __restrict__ decay_logit,
    const float* __restrict__ bw,
    const float* __restrict__ gw,
    const float* __restrict__ fc1_w,
    const float* __restrict__ fc1_b,
    const float* __restrict__ fc2_w,
    const float* __restrict__ fc2_b,
    const float* __restrict__ mod_lr_logit,
    const int*   __restrict__ conn,
    const int*   __restrict__ ws_fl,
    const float4* __restrict__ ws_u,
    float*  __restrict__ ws_ed,
    float*  __restrict__ ws_ep,
    float*  __restrict__ ws_rt,
    float*  __restrict__ ws_h,
    float*  __restrict__ ws_m0,
    float*  __restrict__ out)
{
    const int t   = threadIdx.x;
    const int sub = t >> 5;
    const int d   = t & 31;
    const int n   = blockIdx.x * NPB + sub;

    if (!ws_fl[n]) return;   // fast-path neuron: A's results stand

    __shared__ float ek_r[NPB][2][D];
    __shared__ float rt_r[NPB][2][K];

    const float* f2w = fc2_w + n * (H * 3);
    const float* W = fc1_w + (size_t)n * (MOD_IN * H);
    float o3[2][3];
    #pragma unroll
    for (int b = 0; b < 2; ++b) {
        const size_t base = ((size_t)b * N + n) * D + d;
        float mv[5];
        mv[0] = h_prev[base];
        mv[1] = trace_prim[base];
        mv[2] = trace_key[base];
        mv[3] = primitives[n * D + d];
        mv[4] = key_w[n * D + d];
        float acc0 = 0.f, acc1 = 0.f;
        #pragma unroll
        for (int c = 0; c < 5; ++c) {
            const float mc = mv[c];
            for (int dp = 0; dp < 32; ++dp) {
                const float v = __shfl(mc, dp, 32);
                const float* wr = W + (c * 32 + dp) * H;
                acc0 += v * wr[d];
                acc1 += v * wr[d + 32];
            }
        }
        const float x0 = tanhf(acc0 + fc1_b[n * H + d]);
        const float x1 = tanhf(acc1 + fc1_b[n * H + d + 32]);
        #pragma unroll
        for (int o = 0; o < 3; ++o) {
            float p = x0 * f2w[d * 3 + o] + x1 * f2w[(d + 32) * 3 + o];
            #pragma unroll
            for (int m = 1; m < 32; m <<= 1) p += __shfl_xor(p, m);
            o3[b][o] = p + fc2_b[n * 3 + o];
        }
    }

    const float mlr = sigmoidf_(mod_lr_logit[0]);
    float ep2[2], edc[2];
    #pragma unroll
    for (int b = 0; b < 2; ++b) {
        const size_t base = ((size_t)b * N + n) * D + d;
        const float tp = trace_prim[base];
        const float tk = trace_key[base];
        float sp = tp * tp, sk = tk * tk;
        #pragma unroll
        for (int m = 1; m < 32; m <<= 1) {
            sp += __shfl_xor(sp, m);
            sk += __shfl_xor(sk, m);
        }
        const float gate_prim = tanhf(o3[b][0]);
        const float gate_key  = tanhf(o3[b][1]);
        edc[b] = sigmoidf_(decay_logit[n] + o3[b][2]);
        if (d == 0) ws_ed[b * N + n] = edc[b];
        ep2[b] = primitives[n*D+d] + mlr*gate_prim*(tp / fmaxf(sqrtf(sp), 1e-8f));
        const float ekv = key_w[n*D+d] + mlr*gate_key *(tk / fmaxf(sqrtf(sk), 1e-8f));
        ws_ep[base] = ep2[b];
        ek_r[sub][b][d] = ekv;
    }

    #pragma unroll
    for (int b = 0; b < 2; ++b) {
        const int k = d;
        const int j = conn[n * K + k];
        const float4* pm = reinterpret_cast<const float4*>(
            prev_msgs + ((size_t)b * N + j) * D);
        float s = 0.f;
        #pragma unroll
        for (int q = 0; q < 8; ++q) {
            const float4 v = pm[q];
            s += ek_r[sub][b][q*4+0]*v.x + ek_r[sub][b][q*4+1]*v.y +
                 ek_r[sub][b][q*4+2]*v.z + ek_r[sub][b][q*4+3]*v.w;
        }
        const float rtv = sigmoidf_(s);
        ws_rt[((size_t)b * N + n) * K + k] = rtv;
        rt_r[sub][b][k] = rtv;
    }

    const float4 u = ws_u[n];
    const float* bwn = bw + (size_t)n * (K * D);
    const float* gwn = gw + (size_t)n * 128;
    #pragma unroll
    for (int b = 0; b < 2; ++b) {
        const float* mp = prev_msgs + (size_t)b * N * D;
        float bs[4] = {0.f, 0.f, 0.f, 0.f};
        if (u.x != 0.0f) {
            for (int k = 0; k < 32; ++k)
                bs[k >> 3] += rt_r[sub][b][k] * mp[(size_t)conn[n*K+k] * D + d];
            #pragma unroll
            for (int a = 0; a < 4; ++a) bs[a] *= u.y;
        } else {
            for (int k = 0; k < 32; ++k)
                bs[k >> 3] += rt_r[sub][b][k] * mp[(size_t)conn[n*K+k] * D + d]
                            * bwn[k * 32 + d];
        }
        const float t0 = tanhf(bs[0]), t1 = tanhf(bs[1]),
                    t2 = tanhf(bs[2]), t3 = tanhf(bs[3]);
        const float gsum = (u.z != 0.0f) ? u.w * (t0 + t1 + t2 + t3)
                         : t0*gwn[d] + t1*gwn[32+d] + t2*gwn[64+d] + t3*gwn[96+d];
        float rec = tanhf(gsum);
        const size_t tslot = (size_t)b * (T * C * D) + (size_t)n * D + d;
        if (n < C) rec += cc[tslot];
        const float hn = edc[b] * h_prev[((size_t)b * N + n) * D + d]
                       + (1.f - edc[b]) * rec;
        const float msg = tanhf(hn * ep2[b]);
        ws_h[((size_t)b * N + n) * D + d]  = hn;
        ws_m0[((size_t)b * N + n) * D + d] = msg;
        if (n < C) {
            #pragma unroll
            for (int r = 0; r < STRIDE; ++r)
                out[tslot + (size_t)r * (C * D)] = msg;
        }
    }
}

// ===========================================================================
// Step 1 (full): one thread per (b,n,d), 2048 blocks.
// ===========================================================================
__global__ __launch_bounds__(256) void step_kernel(
    const float*  __restrict__ msg_prev, float* __restrict__ msg_out,
    const float*  __restrict__ h_in, float* __restrict__ h_out,
    const float*  __restrict__ ws_ed, const float* __restrict__ ws_ep,
    const float*  __restrict__ ws_rt, const float4* __restrict__ ws_u,
    const float*  __restrict__ bw, const float* __restrict__ gw,
    const float*  __restrict__ cc, const int* __restrict__ conn,
    float*        __restrict__ out, int step)
{
    const int g    = blockIdx.x * 256 + threadIdx.x;
    const int d    = g & 31;
    const int pair = g >> 5;
    const int n    = pair & (N - 1);
    const int b    = pair >> 13;

    const float4 u = ws_u[n];
    const int4*   jp = reinterpret_cast<const int4*>(conn + n * K);
    const float4* rp = reinterpret_cast<const float4*>(ws_rt + (size_t)pair * K);
    const float*  mp = msg_prev + (size_t)b * N * D;

    float bs[4] = {0.f, 0.f, 0.f, 0.f};
    if (u.x != 0.0f) {
        #pragma unroll
        for (int kk = 0; kk < 8; ++kk) {
            const int4 j4 = jp[kk]; const float4 r4 = rp[kk];
            const int a = kk >> 1;
            bs[a] += r4.x * mp[(size_t)j4.x * D + d];
            bs[a] += r4.y * mp[(size_t)j4.y * D + d];
            bs[a] += r4.z * mp[(size_t)j4.z * D + d];
            bs[a] += r4.w * mp[(size_t)j4.w * D + d];
        }
        #pragma unroll
        for (int a = 0; a < 4; ++a) bs[a] *= u.y;
    } else {
        const float* bwn = bw + (size_t)n * (K * D);
        #pragma unroll
        for (int kk = 0; kk < 8; ++kk) {
            const int4 j4 = jp[kk]; const float4 r4 = rp[kk];
            const int a = kk >> 1;
            bs[a] += r4.x * mp[(size_t)j4.x * D + d] * bwn[(4*kk+0)*32 + d];
            bs[a] += r4.y * mp[(size_t)j4.y * D + d] * bwn[(4*kk+1)*32 + d];
            bs[a] += r4.z * mp[(size_t)j4.z * D + d] * bwn[(4*kk+2)*32 + d];
            bs[a] += r4.w * mp[(size_t)j4.w * D + d] * bwn[(4*kk+3)*32 + d];
        }
    }

    const float t0 = tanhf(bs[0]), t1 = tanhf(bs[1]),
                t2 = tanhf(bs[2]), t3 = tanhf(bs[3]);
    float gsum;
    if (u.z != 0.0f) gsum = u.w * (t0 + t1 + t2 + t3);
    else {
        const float* gwn = gw + (size_t)n * 128;
        gsum = t0*gwn[d] + t1*gwn[32+d] + t2*gwn[64+d] + t3*gwn[96+d];
    }
    float received = tanhf(gsum);

    const size_t tslot = (size_t)b * (T * C * D) +
                         (size_t)(step * STRIDE) * (C * D) + n * D + d;
    if (n < C) received += cc[tslot];

    const float ed = ws_ed[pair];
    const float hn = ed * h_in[(size_t)pair * D + d] + (1.f - ed) * received;
    h_out[(size_t)pair * D + d] = hn;
    const float msg = tanhf(hn * ws_ep[(size_t)pair * D + d]);
    msg_out[(size_t)pair * D + d] = msg;

    if (n < C) {
        #pragma unroll
        for (int r = 0; r < STRIDE; ++r) out[tslot + (size_t)r * (C * D)] = msg;
    }
}

// ===========================================================================
// Sparse steps 2,3 (race-free via separate h buffers).
// ===========================================================================
template<bool USE_LIST>
__global__ __launch_bounds__(256) void step_sparse_kernel(
    const float*  __restrict__ msg_prev, float* __restrict__ msg_out,
    const float*  __restrict__ h_in, float* __restrict__ h_out,
    const float*  __restrict__ ws_ed, const float* __restrict__ ws_ep,
    const float*  __restrict__ ws_rt, const float4* __restrict__ ws_u,
    const float*  __restrict__ bw, const float* __restrict__ gw,
    const float*  __restrict__ cc, const int* __restrict__ conn,
    const int*    __restrict__ ws_list,
    float*        __restrict__ out, int step)
{
    const int i = blockIdx.x * 256 + threadIdx.x;
    const int e = i >> 6;
    const int d = i & 31;
    const int b = (i >> 5) & 1;
    const int n = USE_LIST ? ws_list[e] : e;
    const int pair = b * N + n;

    const float4 u = ws_u[n];
    const int4*   jp = reinterpret_cast<const int4*>(conn + n * K);
    const float4* rp = reinterpret_cast<const float4*>(ws_rt + (size_t)pair * K);
    const float*  mp = msg_prev + (size_t)b * N * D;

    float bs[4] = {0.f, 0.f, 0.f, 0.f};
    if (u.x != 0.0f) {
        #pragma unroll
        for (int kk = 0; kk < 8; ++kk) {
            const int4 j4 = jp[kk]; const float4 r4 = rp[kk];
            const int a = kk >> 1;
            bs[a] += r4.x * mp[(size_t)j4.x * D + d];
            bs[a] += r4.y * mp[(size_t)j4.y * D + d];
            bs[a] += r4.z * mp[(size_t)j4.z * D + d];
            bs[a] += r4.w * mp[(size_t)j4.w * D + d];
        }
        #pragma unroll
        for (int a = 0; a < 4; ++a) bs[a] *= u.y;
    } else {
        const float* bwn = bw + (size_t)n * (K * D);
        #pragma unroll
        for (int kk = 0; kk < 8; ++kk) {
            const int4 j4 = jp[kk]; const float4 r4 = rp[kk];
            const int a = kk >> 1;
            bs[a] += r4.x * mp[(size_t)j4.x * D + d] * bwn[(4*kk+0)*32 + d];
            bs[a] += r4.y * mp[(size_t)j4.y * D + d] * bwn[(4*kk+1)*32 + d];
            bs[a] += r4.z * mp[(size_t)j4.z * D + d] * bwn[(4*kk+2)*32 + d];
            bs[a] += r4.w * mp[(size_t)j4.w * D + d] * bwn[(4*kk+3)*32 + d];
        }
    }

    const float t0 = tanhf(bs[0]), t1 = tanhf(bs[1]),
                t2 = tanhf(bs[2]), t3 = tanhf(bs[3]);
    float gsum;
    if (u.z != 0.0f) gsum = u.w * (t0 + t1 + t2 + t3);
    else {
        const float* gwn = gw + (size_t)n * 128;
        gsum = t0*gwn[d] + t1*gwn[32+d] + t2*gwn[64+d] + t3*gwn[96+d];
    }
    float received = tanhf(gsum);

    const size_t tslot = (size_t)b * (T * C * D) +
                         (size_t)(step * STRIDE) * (C * D) + n * D + d;
    if (n < C) received += cc[tslot];

    const float ed = ws_ed[pair];
    const float hn = ed * h_in[(size_t)pair * D + d] + (1.f - ed) * received;
    h_out[(size_t)pair * D + d] = hn;
    const float msg = tanhf(hn * ws_ep[(size_t)pair * D + d]);
    msg_out[(size_t)pair * D + d] = msg;

    if (n < C) {
        #pragma unroll
        for (int r = 0; r < STRIDE; ++r) out[tslot + (size_t)r * (C * D)] = msg;
    }
}

// ===========================================================================
extern "C" void kernel_launch(void* const* d_in, const int* in_sizes, int n_in,
                              void* d_out, int out_size, void* d_ws, size_t ws_size,
                              hipStream_t stream) {
    const float* cc          = (const float*)d_in[0];
    const float* h_prev      = (const float*)d_in[1];
    const float* prev_msgs   = (const float*)d_in[2];
    const float* trace_prim  = (const float*)d_in[3];
    const float* trace_key   = (const float*)d_in[4];
    const float* primitives  = (const float*)d_in[5];
    const float* key_w       = (const float*)d_in[6];
    const float* decay_logit = (const float*)d_in[7];
    const float* bw          = (const float*)d_in[8];
    const float* gw          = (const float*)d_in[9];
    const float* fc1_w       = (const float*)d_in[10];
    const float* fc1_b       = (const float*)d_in[11];
    const float* fc2_w       = (const float*)d_in[12];
    const float* fc2_b       = (const float*)d_in[13];
    const float* mod_lr      = (const float*)d_in[14];
    const int*   conn        = (const int*)d_in[15];
    // d_in[16] = stride (4, baked into STRIDE)

    float* ws     = (float*)d_ws;
    float* ws_ed  = ws;                       // BS*N
    float* ws_ep  = ws_ed + BS * N;           // BS*N*D
    float* ws_rt  = ws_ep + BS * N * D;       // BS*N*K
    float* ws_h   = ws_rt + BS * N * K;       // BS*N*D
    float* ws_h2  = ws_h  + BS * N * D;       // BS*N*D
    float* ws_m0  = ws_h2 + BS * N * D;       // BS*N*D
    float* ws_m1  = ws_m0 + BS * N * D;       // BS*N*D
    float4* ws_u  = (float4*)(ws_m1 + BS * N * D);  // N float4
    int*   ws_fl  = (int*)(ws_u + N);         // N
    int*   ws_list = ws_fl + N;               // LIST_LEN
    float* outp   = (float*)d_out;

    // A x3 (MEASUREMENT: idempotent; A = (dur - 45.6)/2)
    for (int rep = 0; rep < 3; ++rep) {
        phase1_step0_kernel<<<N / NPB, 256, 0, stream>>>(
            cc, h_prev, prev_msgs, trace_prim, trace_key, primitives, key_w,
            decay_logit, bw, gw, fc2_w, fc2_b, mod_lr, conn,
            ws_ed, ws_ep, ws_rt, ws_u, ws_fl, ws_h, ws_m0, ws_list, outp);
    }

    // R: general-path rescue (no-op when fc2_w slices are all zero)
    rescue_kernel<<<N / NPB, 256, 0, stream>>>(
        cc, h_prev, prev_msgs, trace_prim, trace_key, primitives, key_w,
        decay_logit, bw, gw, fc1_w, fc1_b, fc2_w, fc2_b, mod_lr, conn,
        ws_fl, ws_u, ws_ed, ws_ep, ws_rt, ws_h, ws_m0, outp);

    // B: step 1 (full)
    step_kernel<<<(BS * N * D) / 256, 256, 0, stream>>>(
        ws_m0, ws_m1, ws_h, ws_h, ws_ed, ws_ep, ws_rt, ws_u,
        bw, gw, cc, conn, outp, 1);

    // C: step 2 sparse (race-free: h -> ws_h2)
    step_sparse_kernel<true><<<(LIST_LEN * 64) / 256, 256, 0, stream>>>(
        ws_m1, ws_m0, ws_h, ws_h2, ws_ed, ws_ep, ws_rt, ws_u,
        bw, gw, cc, conn, ws_list, outp, 2);

    // D: step 3 (n < C only; h_out/msg_out go to dead buffers)
    step_sparse_kernel<false><<<(C * 64) / 256, 256, 0, stream>>>(
        ws_m0, ws_m1, ws_h2, ws_h, ws_ed, ws_ep, ws_rt, ws_u,
        bw, gw, cc, conn, ws_list, outp, 3);
}

// Round 14
// 45.066 us; speedup vs baseline: 1.7811x; 1.7811x over previous
//
#include <hip/hip_runtime.h>

// Problem constants (MemoryGraph_15453292331249)
constexpr int N  = 8192;
constexpr int K  = 32;
constexpr int D  = 32;
constexpr int BS = 2;
constexpr int T  = 16;
constexpr int C  = 64;
constexpr int H  = 64;
constexpr int MOD_IN = 5 * D;   // 160
constexpr int STRIDE = 4;
constexpr int NPB = 8;          // neurons (32-lane groups) per block
constexpr int LIST_LEN = C * (K + 1);   // 2112 (with benign duplicates)

__device__ __forceinline__ float sigmoidf_(float x) { return 1.0f / (1.0f + expf(-x)); }

// ===========================================================================
// Kernel A — phase1 hot path (+ fused step 0). Barrier-free; register-batched
// gather (R12). NEW: ultra-fast path when fc2_w slice==0 AND fc2_b[0..1]==0:
// gates are exactly tanh(0)=0 -> eff_prim=primitives, eff_key=key_w; the
// trace loads and norm reductions are algebraically dead. Data-driven with
// full general fallback -> correct for arbitrary inputs.
// ===========================================================================
__global__ __launch_bounds__(256) void phase1_step0_kernel(
    const float* __restrict__ cc,          // (BS,T,C,D)
    const float* __restrict__ h_prev,      // (BS,N,D)
    const float* __restrict__ prev_msgs,   // (BS,N,D)
    const float* __restrict__ trace_prim,  // (BS,N,D)
    const float* __restrict__ trace_key,   // (BS,N,D)
    const float* __restrict__ primitives,  // (N,D)
    const float* __restrict__ key_w,       // (N,D)
    const float* __restrict__ decay_logit, // (N,)
    const float* __restrict__ bw,          // (N,K,D)
    const float* __restrict__ gw,          // (N,4,32)
    const float* __restrict__ fc2_w,       // (N,64,3)
    const float* __restrict__ fc2_b,       // (N,3)
    const float* __restrict__ mod_lr_logit,// (1,)
    const int*   __restrict__ conn,        // (N,K)
    float*  __restrict__ ws_ed,            // (BS,N)
    float*  __restrict__ ws_ep,            // (BS,N,D)
    float*  __restrict__ ws_rt,            // (BS,N,K)
    float4* __restrict__ ws_u,             // (N) {bw_uni, w0, gw_uni, g0}
    int*    __restrict__ ws_fl,            // (N) fc2_w-nonzero flag
    float*  __restrict__ ws_h,             // (BS,N,D) h after step 0
    float*  __restrict__ ws_m0,            // (BS,N,D) msgs after step 0
    int*    __restrict__ ws_list,          // (LIST_LEN)
    float*  __restrict__ out)              // (BS,T,C,D)
{
    const int t   = threadIdx.x;
    const int sub = t >> 5;
    const int d   = t & 31;
    const int n   = blockIdx.x * NPB + sub;

    __shared__ __align__(16) float ek_s[NPB][2][D];
    __shared__ __align__(16) float rows[NPB][K][36];
    __shared__ float rts[NPB][K];

    // ---- fc2_w slice zero-check -> flag (rescue kernel handles nonzero)
    const float* f2w = fc2_w + n * (H * 3);
    int nzf = 0;
    #pragma unroll
    for (int i = 0; i < 6; ++i) nzf |= (f2w[i * 32 + d] != 0.0f);
    #pragma unroll
    for (int m = 1; m < 32; m <<= 1) nzf |= __shfl_xor(nzf, m);
    if (d == 0) ws_fl[n] = nzf;

    // ---- fc2_b gate check: gates = tanh(fc2_b[0..1]) when fc2_w==0
    const float fb0 = fc2_b[n * 3 + 0];
    const float fb1 = fc2_b[n * 3 + 1];
    const float fb2 = fc2_b[n * 3 + 2];
    const int   nzb = (fb0 != 0.0f) | (fb1 != 0.0f);

    const float mlr = sigmoidf_(mod_lr_logit[0]);
    float ep2[2], edc[2];

    if (!nzf && !nzb) {
        // ---- ultra-fast path: gates exactly 0 -> ep=primitives, ek=key_w
        const float pv  = primitives[n * D + d];
        const float kv  = key_w[n * D + d];
        const float edv = sigmoidf_(decay_logit[n] + fb2);
        edc[0] = edv; edc[1] = edv;
        ep2[0] = pv;  ep2[1] = pv;
        if (d == 0) { ws_ed[n] = edv; ws_ed[N + n] = edv; }
        ws_ep[(size_t)n * D + d]       = pv;
        ws_ep[((size_t)N + n) * D + d] = pv;
        ek_s[sub][0][d] = kv;
        ek_s[sub][1][d] = kv;
    } else {
        // ---- general-ish path (o3 = fc2_b; full trace norms). If nzf, the
        //      rescue kernel recomputes and overwrites everything anyway.
        float o3[3] = {fb0, fb1, fb2};
        #pragma unroll
        for (int b = 0; b < 2; ++b) {
            const size_t base = ((size_t)b * N + n) * D + d;
            const float tp = trace_prim[base];
            const float tk = trace_key[base];
            float sp = tp * tp, sk = tk * tk;
            #pragma unroll
            for (int m = 1; m < 32; m <<= 1) {
                sp += __shfl_xor(sp, m);
                sk += __shfl_xor(sk, m);
            }
            const float gate_prim = tanhf(o3[0]);
            const float gate_key  = tanhf(o3[1]);
            edc[b] = sigmoidf_(decay_logit[n] + o3[2]);
            if (d == 0) ws_ed[b * N + n] = edc[b];
            ep2[b] = primitives[n*D+d] + mlr*gate_prim*(tp / fmaxf(sqrtf(sp), 1e-8f));
            const float ekv = key_w[n*D+d] + mlr*gate_key *(tk / fmaxf(sqrtf(sk), 1e-8f));
            ws_ep[base] = ep2[b];
            ek_s[sub][b][d] = ekv;
        }
    }

    // ---- bw/gw per-neuron uniformity check (contiguous float4 loads)
    const float* bwn = bw + (size_t)n * (K * D);
    const float* gwn = gw + (size_t)n * 128;
    const float w0v = bwn[0];
    const float g0v = gwn[0];
    int eqb = 1, eqg;
    {
        const float4* b4 = reinterpret_cast<const float4*>(bwn);
        #pragma unroll
        for (int q = 0; q < 8; ++q) {
            const float4 v = b4[q * 32 + d];
            eqb &= (v.x == w0v) & (v.y == w0v) & (v.z == w0v) & (v.w == w0v);
        }
        const float4 gv = reinterpret_cast<const float4*>(gwn)[d];
        eqg = (gv.x == g0v) & (gv.y == g0v) & (gv.z == g0v) & (gv.w == g0v);
    }
    #pragma unroll
    for (int m = 1; m < 32; m <<= 1) {
        eqb &= __shfl_xor(eqb, m);
        eqg &= __shfl_xor(eqg, m);
    }
    if (d == 0) ws_u[n] = make_float4(eqb ? 1.f : 0.f, w0v, eqg ? 1.f : 0.f, g0v);

    // ---- conn row (one load per lane; reused via shfl) + step-2 list
    const int jme = conn[n * K + d];
    if (n < C) {
        ws_list[n * (K + 1) + d] = jme;
        if (d == 0) ws_list[n * (K + 1) + K] = n;
    }

    // ---- fused scan step 0: register-batched gather
    const float gv0 = gwn[d], gv1 = gwn[32+d], gv2 = gwn[64+d], gv3 = gwn[96+d];
    #pragma unroll
    for (int b = 0; b < 2; ++b) {
        const float* mp = prev_msgs + (size_t)b * N * D;

        float r[32];
        #pragma unroll
        for (int k = 0; k < 32; ++k) {
            const int j = __shfl(jme, k, 32);
            r[k] = mp[(size_t)j * D + d];
        }

        #pragma unroll
        for (int k = 0; k < 32; ++k) rows[sub][k][d] = r[k];

        {
            const int k = d;
            const float4* rw = reinterpret_cast<const float4*>(rows[sub][k]);
            float s = 0.f;
            #pragma unroll
            for (int q = 0; q < 8; ++q) {
                const float4 v = rw[q];
                s += ek_s[sub][b][q*4+0]*v.x + ek_s[sub][b][q*4+1]*v.y +
                     ek_s[sub][b][q*4+2]*v.z + ek_s[sub][b][q*4+3]*v.w;
            }
            const float rtv = sigmoidf_(s);
            ws_rt[((size_t)b * N + n) * K + k] = rtv;
            rts[sub][k] = rtv;
        }

        {
            float bs[4] = {0.f, 0.f, 0.f, 0.f};
            if (eqb) {
                #pragma unroll
                for (int k = 0; k < 32; ++k)
                    bs[k >> 3] += rts[sub][k] * r[k];
                #pragma unroll
                for (int a = 0; a < 4; ++a) bs[a] *= w0v;
            } else {
                #pragma unroll
                for (int k = 0; k < 32; ++k)
                    bs[k >> 3] += rts[sub][k] * r[k] * bwn[k * 32 + d];
            }
            const float t0 = tanhf(bs[0]), t1 = tanhf(bs[1]),
                        t2 = tanhf(bs[2]), t3 = tanhf(bs[3]);
            const float gsum = eqg ? g0v * (t0 + t1 + t2 + t3)
                                   : t0*gv0 + t1*gv1 + t2*gv2 + t3*gv3;
            float rec = tanhf(gsum);
            const size_t tslot = (size_t)b * (T * C * D) + (size_t)n * D + d;  // t=0
            if (n < C) rec += cc[tslot];
            const float hn = edc[b] * h_prev[((size_t)b * N + n) * D + d]
                           + (1.f - edc[b]) * rec;
            const float msg = tanhf(hn * ep2[b]);
            ws_h[((size_t)b * N + n) * D + d]  = hn;
            ws_m0[((size_t)b * N + n) * D + d] = msg;
            if (n < C) {
                #pragma unroll
                for (int r2 = 0; r2 < STRIDE; ++r2)
                    out[tslot + (size_t)r2 * (C * D)] = msg;
            }
        }
    }
}

// ===========================================================================
// Rescue kernel — general path for neurons with nonzero fc2_w slice.
// ===========================================================================
__global__ __launch_bounds__(256) void rescue_kernel(
    const float* __restrict__ cc,
    const float* __restrict__ h_prev,
    const float* __restrict__ prev_msgs,
    const float* __restrict__ trace_prim,
    const float* __restrict__ trace_key,
    const float* __restrict__ primitives,
    const float* __restrict__ key_w,
    const float* __restrict__ decay_logit,
    const float* __restrict__ bw,
    const float* __restrict__ gw,
    const float* __restrict__ fc1_w,
    const float* __restrict__ fc1_b,
    const float* __restrict__ fc2_w,
    const float* __restrict__ fc2_b,
    const float* __restrict__ mod_lr_logit,
    const int*   __restrict__ conn,
    const int*   __restrict__ ws_fl,
    const float4* __restrict__ ws_u,
    float*  __restrict__ ws_ed,
    float*  __restrict__ ws_ep,
    float*  __restrict__ ws_rt,
    float*  __restrict__ ws_h,
    float*  __restrict__ ws_m0,
    float*  __restrict__ out)
{
    const int t   = threadIdx.x;
    const int sub = t >> 5;
    const int d   = t & 31;
    const int n   = blockIdx.x * NPB + sub;

    if (!ws_fl[n]) return;   // fast-path neuron: A's results stand

    __shared__ float ek_r[NPB][2][D];
    __shared__ float rt_r[NPB][2][K];

    const float* f2w = fc2_w + n * (H * 3);
    const float* W = fc1_w + (size_t)n * (MOD_IN * H);
    float o3[2][3];
    #pragma unroll
    for (int b = 0; b < 2; ++b) {
        const size_t base = ((size_t)b * N + n) * D + d;
        float mv[5];
        mv[0] = h_prev[base];
        mv[1] = trace_prim[base];
        mv[2] = trace_key[base];
        mv[3] = primitives[n * D + d];
        mv[4] = key_w[n * D + d];
        float acc0 = 0.f, acc1 = 0.f;
        #pragma unroll
        for (int c = 0; c < 5; ++c) {
            const float mc = mv[c];
            for (int dp = 0; dp < 32; ++dp) {
                const float v = __shfl(mc, dp, 32);
                const float* wr = W + (c * 32 + dp) * H;
                acc0 += v * wr[d];
                acc1 += v * wr[d + 32];
            }
        }
        const float x0 = tanhf(acc0 + fc1_b[n * H + d]);
        const float x1 = tanhf(acc1 + fc1_b[n * H + d + 32]);
        #pragma unroll
        for (int o = 0; o < 3; ++o) {
            float p = x0 * f2w[d * 3 + o] + x1 * f2w[(d + 32) * 3 + o];
            #pragma unroll
            for (int m = 1; m < 32; m <<= 1) p += __shfl_xor(p, m);
            o3[b][o] = p + fc2_b[n * 3 + o];
        }
    }

    const float mlr = sigmoidf_(mod_lr_logit[0]);
    float ep2[2], edc[2];
    #pragma unroll
    for (int b = 0; b < 2; ++b) {
        const size_t base = ((size_t)b * N + n) * D + d;
        const float tp = trace_prim[base];
        const float tk = trace_key[base];
        float sp = tp * tp, sk = tk * tk;
        #pragma unroll
        for (int m = 1; m < 32; m <<= 1) {
            sp += __shfl_xor(sp, m);
            sk += __shfl_xor(sk, m);
        }
        const float gate_prim = tanhf(o3[b][0]);
        const float gate_key  = tanhf(o3[b][1]);
        edc[b] = sigmoidf_(decay_logit[n] + o3[b][2]);
        if (d == 0) ws_ed[b * N + n] = edc[b];
        ep2[b] = primitives[n*D+d] + mlr*gate_prim*(tp / fmaxf(sqrtf(sp), 1e-8f));
        const float ekv = key_w[n*D+d] + mlr*gate_key *(tk / fmaxf(sqrtf(sk), 1e-8f));
        ws_ep[base] = ep2[b];
        ek_r[sub][b][d] = ekv;
    }

    #pragma unroll
    for (int b = 0; b < 2; ++b) {
        const int k = d;
        const int j = conn[n * K + k];
        const float4* pm = reinterpret_cast<const float4*>(
            prev_msgs + ((size_t)b * N + j) * D);
        float s = 0.f;
        #pragma unroll
        for (int q = 0; q < 8; ++q) {
            const float4 v = pm[q];
            s += ek_r[sub][b][q*4+0]*v.x + ek_r[sub][b][q*4+1]*v.y +
                 ek_r[sub][b][q*4+2]*v.z + ek_r[sub][b][q*4+3]*v.w;
        }
        const float rtv = sigmoidf_(s);
        ws_rt[((size_t)b * N + n) * K + k] = rtv;
        rt_r[sub][b][k] = rtv;
    }

    const float4 u = ws_u[n];
    const float* bwn = bw + (size_t)n * (K * D);
    const float* gwn = gw + (size_t)n * 128;
    #pragma unroll
    for (int b = 0; b < 2; ++b) {
        const float* mp = prev_msgs + (size_t)b * N * D;
        float bs[4] = {0.f, 0.f, 0.f, 0.f};
        if (u.x != 0.0f) {
            for (int k = 0; k < 32; ++k)
                bs[k >> 3] += rt_r[sub][b][k] * mp[(size_t)conn[n*K+k] * D + d];
            #pragma unroll
            for (int a = 0; a < 4; ++a) bs[a] *= u.y;
        } else {
            for (int k = 0; k < 32; ++k)
                bs[k >> 3] += rt_r[sub][b][k] * mp[(size_t)conn[n*K+k] * D + d]
                            * bwn[k * 32 + d];
        }
        const float t0 = tanhf(bs[0]), t1 = tanhf(bs[1]),
                    t2 = tanhf(bs[2]), t3 = tanhf(bs[3]);
        const float gsum = (u.z != 0.0f) ? u.w * (t0 + t1 + t2 + t3)
                         : t0*gwn[d] + t1*gwn[32+d] + t2*gwn[64+d] + t3*gwn[96+d];
        float rec = tanhf(gsum);
        const size_t tslot = (size_t)b * (T * C * D) + (size_t)n * D + d;
        if (n < C) rec += cc[tslot];
        const float hn = edc[b] * h_prev[((size_t)b * N + n) * D + d]
                       + (1.f - edc[b]) * rec;
        const float msg = tanhf(hn * ep2[b]);
        ws_h[((size_t)b * N + n) * D + d]  = hn;
        ws_m0[((size_t)b * N + n) * D + d] = msg;
        if (n < C) {
            #pragma unroll
            for (int r = 0; r < STRIDE; ++r)
                out[tslot + (size_t)r * (C * D)] = msg;
        }
    }
}

// ===========================================================================
// Step 1 (full): one thread per (b,n,d), 2048 blocks.
// ===========================================================================
__global__ __launch_bounds__(256) void step_kernel(
    const float*  __restrict__ msg_prev, float* __restrict__ msg_out,
    const float*  __restrict__ h_in, float* __restrict__ h_out,
    const float*  __restrict__ ws_ed, const float* __restrict__ ws_ep,
    const float*  __restrict__ ws_rt, const float4* __restrict__ ws_u,
    const float*  __restrict__ bw, const float* __restrict__ gw,
    const float*  __restrict__ cc, const int* __restrict__ conn,
    float*        __restrict__ out, int step)
{
    const int g    = blockIdx.x * 256 + threadIdx.x;
    const int d    = g & 31;
    const int pair = g >> 5;
    const int n    = pair & (N - 1);
    const int b    = pair >> 13;

    const float4 u = ws_u[n];
    const int4*   jp = reinterpret_cast<const int4*>(conn + n * K);
    const float4* rp = reinterpret_cast<const float4*>(ws_rt + (size_t)pair * K);
    const float*  mp = msg_prev + (size_t)b * N * D;

    float bs[4] = {0.f, 0.f, 0.f, 0.f};
    if (u.x != 0.0f) {
        #pragma unroll
        for (int kk = 0; kk < 8; ++kk) {
            const int4 j4 = jp[kk]; const float4 r4 = rp[kk];
            const int a = kk >> 1;
            bs[a] += r4.x * mp[(size_t)j4.x * D + d];
            bs[a] += r4.y * mp[(size_t)j4.y * D + d];
            bs[a] += r4.z * mp[(size_t)j4.z * D + d];
            bs[a] += r4.w * mp[(size_t)j4.w * D + d];
        }
        #pragma unroll
        for (int a = 0; a < 4; ++a) bs[a] *= u.y;
    } else {
        const float* bwn = bw + (size_t)n * (K * D);
        #pragma unroll
        for (int kk = 0; kk < 8; ++kk) {
            const int4 j4 = jp[kk]; const float4 r4 = rp[kk];
            const int a = kk >> 1;
            bs[a] += r4.x * mp[(size_t)j4.x * D + d] * bwn[(4*kk+0)*32 + d];
            bs[a] += r4.y * mp[(size_t)j4.y * D + d] * bwn[(4*kk+1)*32 + d];
            bs[a] += r4.z * mp[(size_t)j4.z * D + d] * bwn[(4*kk+2)*32 + d];
            bs[a] += r4.w * mp[(size_t)j4.w * D + d] * bwn[(4*kk+3)*32 + d];
        }
    }

    const float t0 = tanhf(bs[0]), t1 = tanhf(bs[1]),
                t2 = tanhf(bs[2]), t3 = tanhf(bs[3]);
    float gsum;
    if (u.z != 0.0f) gsum = u.w * (t0 + t1 + t2 + t3);
    else {
        const float* gwn = gw + (size_t)n * 128;
        gsum = t0*gwn[d] + t1*gwn[32+d] + t2*gwn[64+d] + t3*gwn[96+d];
    }
    float received = tanhf(gsum);

    const size_t tslot = (size_t)b * (T * C * D) +
                         (size_t)(step * STRIDE) * (C * D) + n * D + d;
    if (n < C) received += cc[tslot];

    const float ed = ws_ed[pair];
    const float hn = ed * h_in[(size_t)pair * D + d] + (1.f - ed) * received;
    h_out[(size_t)pair * D + d] = hn;
    const float msg = tanhf(hn * ws_ep[(size_t)pair * D + d]);
    msg_out[(size_t)pair * D + d] = msg;

    if (n < C) {
        #pragma unroll
        for (int r = 0; r < STRIDE; ++r) out[tslot + (size_t)r * (C * D)] = msg;
    }
}

// ===========================================================================
// Sparse steps 2,3 (race-free via separate h buffers).
// ===========================================================================
template<bool USE_LIST>
__global__ __launch_bounds__(256) void step_sparse_kernel(
    const float*  __restrict__ msg_prev, float* __restrict__ msg_out,
    const float*  __restrict__ h_in, float* __restrict__ h_out,
    const float*  __restrict__ ws_ed, const float* __restrict__ ws_ep,
    const float*  __restrict__ ws_rt, const float4* __restrict__ ws_u,
    const float*  __restrict__ bw, const float* __restrict__ gw,
    const float*  __restrict__ cc, const int* __restrict__ conn,
    const int*    __restrict__ ws_list,
    float*        __restrict__ out, int step)
{
    const int i = blockIdx.x * 256 + threadIdx.x;
    const int e = i >> 6;
    const int d = i & 31;
    const int b = (i >> 5) & 1;
    const int n = USE_LIST ? ws_list[e] : e;
    const int pair = b * N + n;

    const float4 u = ws_u[n];
    const int4*   jp = reinterpret_cast<const int4*>(conn + n * K);
    const float4* rp = reinterpret_cast<const float4*>(ws_rt + (size_t)pair * K);
    const float*  mp = msg_prev + (size_t)b * N * D;

    float bs[4] = {0.f, 0.f, 0.f, 0.f};
    if (u.x != 0.0f) {
        #pragma unroll
        for (int kk = 0; kk < 8; ++kk) {
            const int4 j4 = jp[kk]; const float4 r4 = rp[kk];
            const int a = kk >> 1;
            bs[a] += r4.x * mp[(size_t)j4.x * D + d];
            bs[a] += r4.y * mp[(size_t)j4.y * D + d];
            bs[a] += r4.z * mp[(size_t)j4.z * D + d];
            bs[a] += r4.w * mp[(size_t)j4.w * D + d];
        }
        #pragma unroll
        for (int a = 0; a < 4; ++a) bs[a] *= u.y;
    } else {
        const float* bwn = bw + (size_t)n * (K * D);
        #pragma unroll
        for (int kk = 0; kk < 8; ++kk) {
            const int4 j4 = jp[kk]; const float4 r4 = rp[kk];
            const int a = kk >> 1;
            bs[a] += r4.x * mp[(size_t)j4.x * D + d] * bwn[(4*kk+0)*32 + d];
            bs[a] += r4.y * mp[(size_t)j4.y * D + d] * bwn[(4*kk+1)*32 + d];
            bs[a] += r4.z * mp[(size_t)j4.z * D + d] * bwn[(4*kk+2)*32 + d];
            bs[a] += r4.w * mp[(size_t)j4.w * D + d] * bwn[(4*kk+3)*32 + d];
        }
    }

    const float t0 = tanhf(bs[0]), t1 = tanhf(bs[1]),
                t2 = tanhf(bs[2]), t3 = tanhf(bs[3]);
    float gsum;
    if (u.z != 0.0f) gsum = u.w * (t0 + t1 + t2 + t3);
    else {
        const float* gwn = gw + (size_t)n * 128;
        gsum = t0*gwn[d] + t1*gwn[32+d] + t2*gwn[64+d] + t3*gwn[96+d];
    }
    float received = tanhf(gsum);

    const size_t tslot = (size_t)b * (T * C * D) +
                         (size_t)(step * STRIDE) * (C * D) + n * D + d;
    if (n < C) received += cc[tslot];

    const float ed = ws_ed[pair];
    const float hn = ed * h_in[(size_t)pair * D + d] + (1.f - ed) * received;
    h_out[(size_t)pair * D + d] = hn;
    const float msg = tanhf(hn * ws_ep[(size_t)pair * D + d]);
    msg_out[(size_t)pair * D + d] = msg;

    if (n < C) {
        #pragma unroll
        for (int r = 0; r < STRIDE; ++r) out[tslot + (size_t)r * (C * D)] = msg;
    }
}

// ===========================================================================
extern "C" void kernel_launch(void* const* d_in, const int* in_sizes, int n_in,
                              void* d_out, int out_size, void* d_ws, size_t ws_size,
                              hipStream_t stream) {
    const float* cc          = (const float*)d_in[0];
    const float* h_prev      = (const float*)d_in[1];
    const float* prev_msgs   = (const float*)d_in[2];
    const float* trace_prim  = (const float*)d_in[3];
    const float* trace_key   = (const float*)d_in[4];
    const float* primitives  = (const float*)d_in[5];
    const float* key_w       = (const float*)d_in[6];
    const float* decay_logit = (const float*)d_in[7];
    const float* bw          = (const float*)d_in[8];
    const float* gw          = (const float*)d_in[9];
    const float* fc1_w       = (const float*)d_in[10];
    const float* fc1_b       = (const float*)d_in[11];
    const float* fc2_w       = (const float*)d_in[12];
    const float* fc2_b       = (const float*)d_in[13];
    const float* mod_lr      = (const float*)d_in[14];
    const int*   conn        = (const int*)d_in[15];
    // d_in[16] = stride (4, baked into STRIDE)

    float* ws     = (float*)d_ws;
    float* ws_ed  = ws;                       // BS*N
    float* ws_ep  = ws_ed + BS * N;           // BS*N*D
    float* ws_rt  = ws_ep + BS * N * D;       // BS*N*K
    float* ws_h   = ws_rt + BS * N * K;       // BS*N*D
    float* ws_h2  = ws_h  + BS * N * D;       // BS*N*D
    float* ws_m0  = ws_h2 + BS * N * D;       // BS*N*D
    float* ws_m1  = ws_m0 + BS * N * D;       // BS*N*D
    float4* ws_u  = (float4*)(ws_m1 + BS * N * D);  // N float4
    int*   ws_fl  = (int*)(ws_u + N);         // N
    int*   ws_list = ws_fl + N;               // LIST_LEN
    float* outp   = (float*)d_out;

    // A: phase1 hot + step 0 (ultra-fast gate path)
    phase1_step0_kernel<<<N / NPB, 256, 0, stream>>>(
        cc, h_prev, prev_msgs, trace_prim, trace_key, primitives, key_w,
        decay_logit, bw, gw, fc2_w, fc2_b, mod_lr, conn,
        ws_ed, ws_ep, ws_rt, ws_u, ws_fl, ws_h, ws_m0, ws_list, outp);

    // R: general-path rescue (no-op when fc2_w slices are all zero)
    rescue_kernel<<<N / NPB, 256, 0, stream>>>(
        cc, h_prev, prev_msgs, trace_prim, trace_key, primitives, key_w,
        decay_logit, bw, gw, fc1_w, fc1_b, fc2_w, fc2_b, mod_lr, conn,
        ws_fl, ws_u, ws_ed, ws_ep, ws_rt, ws_h, ws_m0, outp);

    // B: step 1 (full)
    step_kernel<<<(BS * N * D) / 256, 256, 0, stream>>>(
        ws_m0, ws_m1, ws_h, ws_h, ws_ed, ws_ep, ws_rt, ws_u,
        bw, gw, cc, conn, outp, 1);

    // C: step 2 sparse (race-free: h -> ws_h2)
    step_sparse_kernel<true><<<(LIST_LEN * 64) / 256, 256, 0, stream>>>(
        ws_m1, ws_m0, ws_h, ws_h2, ws_ed, ws_ep, ws_rt, ws_u,
        bw, gw, cc, conn, ws_list, outp, 2);

    // D: step 3 (n < C only; h_out/msg_out go to dead buffers)
    step_sparse_kernel<false><<<(C * 64) / 256, 256, 0, stream>>>(
        ws_m0, ws_m1, ws_h2, ws_h, ws_ed, ws_ep, ws_rt, ws_u,
        bw, gw, cc, conn, ws_list, outp, 3);
}